// Round 2
// baseline (951.026 us; speedup 1.0000x reference)
//
#include <hip/hip_runtime.h>
#include <cstdint>

#define NEG_SLOPE 0.2f
#define LN_EPS 1e-5f

typedef __bf16 bf16x8 __attribute__((ext_vector_type(8)));
typedef float f32x4 __attribute__((ext_vector_type(4)));

__device__ __forceinline__ float b2f(unsigned int u) {
    union { unsigned int i; float f; } x; x.i = u << 16; return x.f;
}
__device__ __forceinline__ unsigned short f2b(float f) {
    union { float f; unsigned int i; } x; x.f = f;
    unsigned int r = x.i + 0x7fffu + ((x.i >> 16) & 1u);
    return (unsigned short)(r >> 16);
}

// ---------------- k0a: fold attention vectors into projections (all fp32) --------
// u_src[k][h] = sum_c W[k][h*32+c]*att_src[h][c]; u_dst likewise; vW from W_e/att_edge.
__global__ void k0a_prep(const float* __restrict__ W,
                         const float* __restrict__ We,
                         const float* __restrict__ att_src,
                         const float* __restrict__ att_dst,
                         const float* __restrict__ att_edge,
                         float* __restrict__ u_src, float* __restrict__ u_dst,
                         float* __restrict__ vW) {
    int t = threadIdx.x;  // 256
    const float* wr = W + t * 256;
    for (int h = 0; h < 8; h++) {
        float s1 = 0.f, s2 = 0.f;
        for (int c = 0; c < 32; c++) {
            float w = wr[h * 32 + c];
            s1 += w * att_src[h * 32 + c];
            s2 += w * att_dst[h * 32 + c];
        }
        u_src[t * 8 + h] = s1; u_dst[t * 8 + h] = s2;
    }
    if (t < 64) {
        const float* er = We + t * 256;
        for (int h = 0; h < 8; h++) {
            float s = 0.f;
            for (int c = 0; c < 32; c++) s += er[h * 32 + c] * att_edge[h * 32 + c];
            vW[t * 8 + h] = s;
        }
    }
}

// ---------------- k0b: transpose W (256x256 fp32) -> bf16 Wt for MFMA B-frags ------
__global__ void k0b_transpose(const float* __restrict__ W,
                              unsigned short* __restrict__ Wt) {
    int n = blockIdx.x;   // col of W  -> row of Wt
    int k = threadIdx.x;  // row of W
    Wt[n * 256 + k] = f2b(W[k * 256 + n]);
}

// ---------------- k1: xp = bf16(x) @ bf16(W) via MFMA 16x16x32, fp32 accum ---------
// block = 4 waves; tile 16 rows x 256 cols; wave handles 4 col-tiles of 16.
__global__ __launch_bounds__(256) void k1_xp(const float* __restrict__ x,
                                             const unsigned short* __restrict__ Wt,
                                             unsigned short* __restrict__ xp, int N) {
    int m0 = blockIdx.x * 16;
    int lane = threadIdx.x & 63, wave = threadIdx.x >> 6;
    int quad = lane >> 4, l16 = lane & 15;
    int mrow = m0 + l16; if (mrow > N - 1) mrow = N - 1;
    const float* ap = x + mrow * 256 + quad * 8;
    const unsigned short* bp0 = Wt + (wave * 64 + l16) * 256 + quad * 8;
    const unsigned short* bp1 = bp0 + 16 * 256;
    const unsigned short* bp2 = bp0 + 32 * 256;
    const unsigned short* bp3 = bp0 + 48 * 256;
    f32x4 ac0 = {0,0,0,0}, ac1 = {0,0,0,0}, ac2 = {0,0,0,0}, ac3 = {0,0,0,0};
#pragma unroll
    for (int kk = 0; kk < 8; kk++) {
        float4 fa0 = *(const float4*)(ap + kk * 32);
        float4 fa1 = *(const float4*)(ap + kk * 32 + 4);
        union { unsigned short u[8]; bf16x8 v; } A;
        A.u[0] = f2b(fa0.x); A.u[1] = f2b(fa0.y); A.u[2] = f2b(fa0.z); A.u[3] = f2b(fa0.w);
        A.u[4] = f2b(fa1.x); A.u[5] = f2b(fa1.y); A.u[6] = f2b(fa1.z); A.u[7] = f2b(fa1.w);
        bf16x8 b0 = *(const bf16x8*)(bp0 + kk * 32);
        bf16x8 b1 = *(const bf16x8*)(bp1 + kk * 32);
        bf16x8 b2 = *(const bf16x8*)(bp2 + kk * 32);
        bf16x8 b3 = *(const bf16x8*)(bp3 + kk * 32);
        ac0 = __builtin_amdgcn_mfma_f32_16x16x32_bf16(A.v, b0, ac0, 0, 0, 0);
        ac1 = __builtin_amdgcn_mfma_f32_16x16x32_bf16(A.v, b1, ac1, 0, 0, 0);
        ac2 = __builtin_amdgcn_mfma_f32_16x16x32_bf16(A.v, b2, ac2, 0, 0, 0);
        ac3 = __builtin_amdgcn_mfma_f32_16x16x32_bf16(A.v, b3, ac3, 0, 0, 0);
    }
    int nb = wave * 64;
#pragma unroll
    for (int r = 0; r < 4; r++) {
        int m = m0 + quad * 4 + r;
        if (m < N) {
            unsigned short* op = xp + m * 256 + nb + l16;
            op[0]  = f2b(ac0[r]); op[16] = f2b(ac1[r]);
            op[32] = f2b(ac2[r]); op[48] = f2b(ac3[r]);
        }
    }
}

// ---------------- k1b: a_src/a_dst = x @ u_{src,dst} (fp32, uniform u -> s_loads) --
__global__ __launch_bounds__(256) void k1b_ad(const float* __restrict__ x,
                                              const float* __restrict__ u_src,
                                              const float* __restrict__ u_dst,
                                              float* __restrict__ a_src,
                                              float* __restrict__ a_dst, int N) {
    int n = blockIdx.x * 256 + threadIdx.x;
    if (n >= N) return;
    const float4* xr = (const float4*)(x + n * 256);
    float as[8] = {0,0,0,0,0,0,0,0}, ad[8] = {0,0,0,0,0,0,0,0};
    for (int kk = 0; kk < 64; kk++) {
        float4 u = xr[kk];
        float f[4] = {u.x, u.y, u.z, u.w};
#pragma unroll
        for (int j = 0; j < 4; j++) {
            int k = kk * 4 + j;
#pragma unroll
            for (int h = 0; h < 8; h++) {
                as[h] += f[j] * u_src[k * 8 + h];
                ad[h] += f[j] * u_dst[k * 8 + h];
            }
        }
    }
    float4* po = (float4*)(a_src + n * 8);
    po[0] = make_float4(as[0], as[1], as[2], as[3]);
    po[1] = make_float4(as[4], as[5], as[6], as[7]);
    float4* pd = (float4*)(a_dst + n * 8);
    pd[0] = make_float4(ad[0], ad[1], ad[2], ad[3]);
    pd[1] = make_float4(ad[4], ad[5], ad[6], ad[7]);
}

// ---------------- k2: per-edge logits, exp (no max-sub needed), den/deg atomics ----
__global__ __launch_bounds__(256) void k2_edge(const int* __restrict__ ei,
                                               const float* __restrict__ eattr,
                                               const float* __restrict__ vW,
                                               const float* __restrict__ a_src,
                                               const float* __restrict__ a_dst,
                                               unsigned short* __restrict__ ea,
                                               float* __restrict__ den,
                                               int* __restrict__ deg, int E) {
    int e = blockIdx.x * 256 + threadIdx.x;
    if (e >= E) return;
    int s = ei[e], d = ei[E + e];
    float acc[8] = {0,0,0,0,0,0,0,0};
    const float4* ar = (const float4*)(eattr + e * 64);
    for (int kk = 0; kk < 16; kk++) {
        float4 u = ar[kk];
        float f[4] = {u.x, u.y, u.z, u.w};
#pragma unroll
        for (int j = 0; j < 4; j++) {
            int k = kk * 4 + j;
#pragma unroll
            for (int h = 0; h < 8; h++) acc[h] += f[j] * vW[k * 8 + h];
        }
    }
    const float4* asp = (const float4*)(a_src + s * 8);
    const float4* adp = (const float4*)(a_dst + d * 8);
    float4 as0 = asp[0], as1 = asp[1], ad0 = adp[0], ad1 = adp[1];
    float asv[8] = {as0.x, as0.y, as0.z, as0.w, as1.x, as1.y, as1.z, as1.w};
    float adv[8] = {ad0.x, ad0.y, ad0.z, ad0.w, ad1.x, ad1.y, ad1.z, ad1.w};
    float* dend = den + d * 8;
    unsigned short pk[8];
#pragma unroll
    for (int h = 0; h < 8; h++) {
        float al = asv[h] + adv[h] + acc[h];
        al = (al > 0.f) ? al : NEG_SLOPE * al;
        float ex = __expf(al);
        atomicAdd(dend + h, ex);
        pk[h] = f2b(ex);
    }
    uint4 st;
    st.x = (unsigned)pk[0] | ((unsigned)pk[1] << 16);
    st.y = (unsigned)pk[2] | ((unsigned)pk[3] << 16);
    st.z = (unsigned)pk[4] | ((unsigned)pk[5] << 16);
    st.w = (unsigned)pk[6] | ((unsigned)pk[7] << 16);
    ((uint4*)ea)[e] = st;
    atomicAdd(deg + d, 1);
}

// ---------------- k3: 3-phase exclusive scan of degrees -> CSR rowptr --------------
__global__ __launch_bounds__(1024) void k3a_scan(const int* __restrict__ deg,
                                                 int* __restrict__ rowptr,
                                                 int* __restrict__ bsum, int N) {
    __shared__ int s[1024];
    int t = threadIdx.x, i = blockIdx.x * 1024 + t;
    int v = (i < N) ? deg[i] : 0;
    s[t] = v; __syncthreads();
    for (int off = 1; off < 1024; off <<= 1) {
        int add = (t >= off) ? s[t - off] : 0;
        __syncthreads();
        s[t] += add;
        __syncthreads();
    }
    if (i < N) rowptr[i] = s[t] - v;
    if (t == 1023) bsum[blockIdx.x] = s[1023];
}
__global__ void k3b_scan(const int* __restrict__ bsum, int* __restrict__ boff, int nb) {
    if (threadIdx.x == 0) {
        int run = 0;
        for (int i = 0; i < nb; i++) { boff[i] = run; run += bsum[i]; }
    }
}
__global__ __launch_bounds__(1024) void k3c_add(int* __restrict__ rowptr,
                                                int* __restrict__ cursor,
                                                const int* __restrict__ boff, int N, int E) {
    int i = blockIdx.x * 1024 + threadIdx.x;
    if (i < N) {
        int r = rowptr[i] + boff[blockIdx.x];
        rowptr[i] = r; cursor[i] = r;
    }
    if (i == 0) rowptr[N] = E;
}
__global__ __launch_bounds__(256) void k3d_scatter(const int* __restrict__ ei,
                                                   int* __restrict__ cursor,
                                                   int* __restrict__ perm, int E) {
    int e = blockIdx.x * 256 + threadIdx.x;
    if (e >= E) return;
    int d = ei[E + e];
    int p = atomicAdd(cursor + d, 1);
    perm[p] = e;
}

// ---------------- k4: per-node gather + softmax-normalize + bias + residual + LN ---
// one wave per node; lane handles 4 channels (head = lane>>3).
__global__ __launch_bounds__(64) void k4_agg(const float* __restrict__ xin,
                                             const unsigned short* __restrict__ xp,
                                             const unsigned short* __restrict__ ea,
                                             const float* __restrict__ den,
                                             const int* __restrict__ rowptr,
                                             const int* __restrict__ perm,
                                             const int* __restrict__ ei,
                                             const float* __restrict__ bias,
                                             const float* __restrict__ gamma,
                                             const float* __restrict__ beta,
                                             float* __restrict__ out, int N) {
    __shared__ int ssrc[64];
    __shared__ float sattn[64 * 9];  // pad 8->9 to break bank conflicts
    __shared__ float sinv[8];
    int n = blockIdx.x, l = threadIdx.x;
    if (l < 8) sinv[l] = 1.0f / (den[n * 8 + l] + 1e-16f);
    __syncthreads();
    int start = rowptr[n], end = rowptr[n + 1];
    float a0 = 0.f, a1 = 0.f, a2 = 0.f, a3 = 0.f;
    int hh = l >> 3;  // head for channels l*4..l*4+3
    for (int base = start; base < end; base += 64) {
        int cnt = end - base; if (cnt > 64) cnt = 64;
        if (l < cnt) {
            int e = perm[base + l];
            ssrc[l] = ei[e];
            uint4 u = ((const uint4*)ea)[e];
            float* sp = sattn + l * 9;
            sp[0] = b2f(u.x & 0xffffu) * sinv[0]; sp[1] = b2f(u.x >> 16) * sinv[1];
            sp[2] = b2f(u.y & 0xffffu) * sinv[2]; sp[3] = b2f(u.y >> 16) * sinv[3];
            sp[4] = b2f(u.z & 0xffffu) * sinv[4]; sp[5] = b2f(u.z >> 16) * sinv[5];
            sp[6] = b2f(u.w & 0xffffu) * sinv[6]; sp[7] = b2f(u.w >> 16) * sinv[7];
        }
        __syncthreads();
        for (int i = 0; i < cnt; i++) {
            int s = ssrc[i];
            uint2 u = *(const uint2*)(xp + s * 256 + l * 4);
            float w = sattn[i * 9 + hh];
            a0 += b2f(u.x & 0xffffu) * w; a1 += b2f(u.x >> 16) * w;
            a2 += b2f(u.y & 0xffffu) * w; a3 += b2f(u.y >> 16) * w;
        }
        __syncthreads();
    }
    float4 xv = *(const float4*)(xin + n * 256 + l * 4);
    float4 bv = *(const float4*)(bias + l * 4);
    float y0 = xv.x + a0 + bv.x;
    float y1 = xv.y + a1 + bv.y;
    float y2 = xv.z + a2 + bv.z;
    float y3 = xv.w + a3 + bv.w;
    float s1 = y0 + y1 + y2 + y3;
    float s2 = y0 * y0 + y1 * y1 + y2 * y2 + y3 * y3;
#pragma unroll
    for (int o = 32; o > 0; o >>= 1) {
        s1 += __shfl_down(s1, o, 64);
        s2 += __shfl_down(s2, o, 64);
    }
    s1 = __shfl(s1, 0, 64); s2 = __shfl(s2, 0, 64);
    float mu = s1 * (1.f / 256.f);
    float var = s2 * (1.f / 256.f) - mu * mu;
    float rs = rsqrtf(var + LN_EPS);
    float4 gv  = *(const float4*)(gamma + l * 4);
    float4 btv = *(const float4*)(beta + l * 4);
    float4 ov;
    ov.x = (y0 - mu) * rs * gv.x + btv.x;
    ov.y = (y1 - mu) * rs * gv.y + btv.y;
    ov.z = (y2 - mu) * rs * gv.z + btv.z;
    ov.w = (y3 - mu) * rs * gv.w + btv.w;
    *(float4*)(out + n * 256 + l * 4) = ov;
}

extern "C" void kernel_launch(void* const* d_in, const int* in_sizes, int n_in,
                              void* d_out, int out_size, void* d_ws, size_t ws_size,
                              hipStream_t stream) {
    const float* x     = (const float*)d_in[0];
    const int*   ei    = (const int*)d_in[1];
    const float* eattr = (const float*)d_in[2];
    const float* W     = (const float*)d_in[3];
    const float* We    = (const float*)d_in[4];
    const float* atts  = (const float*)d_in[5];
    const float* attd  = (const float*)d_in[6];
    const float* atte  = (const float*)d_in[7];
    const float* bias  = (const float*)d_in[8];
    const float* gamma = (const float*)d_in[9];
    const float* beta  = (const float*)d_in[10];
    float* out = (float*)d_out;
    int N = in_sizes[0] / 256;
    int E = in_sizes[1] / 2;

    char* p = (char*)d_ws;
    auto carve = [&](size_t bytes) -> void* {
        void* r = (void*)p; p += (bytes + 255) & ~(size_t)255; return r;
    };
    unsigned short* xp = (unsigned short*)carve((size_t)N * 256 * 2);  // bf16
    unsigned short* ea = (unsigned short*)carve((size_t)E * 8 * 2);    // bf16
    float* a_src       = (float*)carve((size_t)N * 8 * 4);
    float* a_dst       = (float*)carve((size_t)N * 8 * 4);
    float* den         = (float*)carve((size_t)N * 8 * 4);   // zeroed below
    int*   deg         = (int*)carve((size_t)N * 4);         // zeroed (adjacent)
    int*   rowptr      = (int*)carve((size_t)(N + 1) * 4);
    int*   cursor      = (int*)carve((size_t)N * 4);
    int*   perm        = (int*)carve((size_t)E * 4);
    int*   bsum        = (int*)carve(1024);
    int*   boff        = (int*)carve(1024);
    float* u_src       = (float*)carve(2048 * 4);
    float* u_dst       = (float*)carve(2048 * 4);
    float* vW          = (float*)carve(512 * 4);
    unsigned short* Wt = (unsigned short*)carve(65536 * 2);

    hipMemsetAsync(den, 0, (size_t)((char*)rowptr - (char*)den), stream);

    hipLaunchKernelGGL(k0a_prep, dim3(1), dim3(256), 0, stream,
                       W, We, atts, attd, atte, u_src, u_dst, vW);
    hipLaunchKernelGGL(k0b_transpose, dim3(256), dim3(256), 0, stream, W, Wt);
    hipLaunchKernelGGL(k1_xp, dim3((N + 15) / 16), dim3(256), 0, stream, x, Wt, xp, N);
    hipLaunchKernelGGL(k1b_ad, dim3((N + 255) / 256), dim3(256), 0, stream,
                       x, u_src, u_dst, a_src, a_dst, N);
    hipLaunchKernelGGL(k2_edge, dim3((E + 255) / 256), dim3(256), 0, stream,
                       ei, eattr, vW, a_src, a_dst, ea, den, deg, E);
    int nb = (N + 1023) / 1024;
    hipLaunchKernelGGL(k3a_scan, dim3(nb), dim3(1024), 0, stream, deg, rowptr, bsum, N);
    hipLaunchKernelGGL(k3b_scan, dim3(1), dim3(64), 0, stream, bsum, boff, nb);
    hipLaunchKernelGGL(k3c_add, dim3(nb), dim3(1024), 0, stream, rowptr, cursor, boff, N, E);
    hipLaunchKernelGGL(k3d_scatter, dim3((E + 255) / 256), dim3(256), 0, stream,
                       ei, cursor, perm, E);
    hipLaunchKernelGGL(k4_agg, dim3(N), dim3(64), 0, stream,
                       x, xp, ea, den, rowptr, perm, ei, bias, gamma, beta, out, N);
}

// Round 3
// 669.785 us; speedup vs baseline: 1.4199x; 1.4199x over previous
//
#include <hip/hip_runtime.h>
#include <cstdint>

#define NEG_SLOPE 0.2f
#define LN_EPS 1e-5f

typedef __bf16 bf16x8 __attribute__((ext_vector_type(8)));
typedef float f32x4 __attribute__((ext_vector_type(4)));

__device__ __forceinline__ float b2f(unsigned int u) {
    union { unsigned int i; float f; } x; x.i = u << 16; return x.f;
}
__device__ __forceinline__ unsigned short f2b(float f) {
    union { float f; unsigned int i; } x; x.f = f;
    unsigned int r = x.i + 0x7fffu + ((x.i >> 16) & 1u);
    return (unsigned short)(r >> 16);
}

// ---------------- k0a: fold attention vectors into projections (all fp32) --------
__global__ void k0a_prep(const float* __restrict__ W,
                         const float* __restrict__ We,
                         const float* __restrict__ att_src,
                         const float* __restrict__ att_dst,
                         const float* __restrict__ att_edge,
                         float* __restrict__ u_src, float* __restrict__ u_dst,
                         float* __restrict__ vW) {
    int t = threadIdx.x;  // 256
    const float* wr = W + t * 256;
    for (int h = 0; h < 8; h++) {
        float s1 = 0.f, s2 = 0.f;
        for (int c = 0; c < 32; c++) {
            float w = wr[h * 32 + c];
            s1 += w * att_src[h * 32 + c];
            s2 += w * att_dst[h * 32 + c];
        }
        u_src[t * 8 + h] = s1; u_dst[t * 8 + h] = s2;
    }
    if (t < 64) {
        const float* er = We + t * 256;
        for (int h = 0; h < 8; h++) {
            float s = 0.f;
            for (int c = 0; c < 32; c++) s += er[h * 32 + c] * att_edge[h * 32 + c];
            vW[t * 8 + h] = s;
        }
    }
}

// ---------------- k0b: transpose W (256x256 fp32) -> bf16 Wt for MFMA B-frags ------
__global__ void k0b_transpose(const float* __restrict__ W,
                              unsigned short* __restrict__ Wt) {
    int n = blockIdx.x;   // col of W  -> row of Wt
    int k = threadIdx.x;  // row of W
    Wt[n * 256 + k] = f2b(W[k * 256 + n]);
}

// ---------------- k1: xp = bf16(x) @ bf16(W) via MFMA 16x16x32, fp32 accum ---------
__global__ __launch_bounds__(256) void k1_xp(const float* __restrict__ x,
                                             const unsigned short* __restrict__ Wt,
                                             unsigned short* __restrict__ xp, int N) {
    int m0 = blockIdx.x * 16;
    int lane = threadIdx.x & 63, wave = threadIdx.x >> 6;
    int quad = lane >> 4, l16 = lane & 15;
    int mrow = m0 + l16; if (mrow > N - 1) mrow = N - 1;
    const float* ap = x + mrow * 256 + quad * 8;
    const unsigned short* bp0 = Wt + (wave * 64 + l16) * 256 + quad * 8;
    const unsigned short* bp1 = bp0 + 16 * 256;
    const unsigned short* bp2 = bp0 + 32 * 256;
    const unsigned short* bp3 = bp0 + 48 * 256;
    f32x4 ac0 = {0,0,0,0}, ac1 = {0,0,0,0}, ac2 = {0,0,0,0}, ac3 = {0,0,0,0};
#pragma unroll
    for (int kk = 0; kk < 8; kk++) {
        float4 fa0 = *(const float4*)(ap + kk * 32);
        float4 fa1 = *(const float4*)(ap + kk * 32 + 4);
        union { unsigned short u[8]; bf16x8 v; } A;
        A.u[0] = f2b(fa0.x); A.u[1] = f2b(fa0.y); A.u[2] = f2b(fa0.z); A.u[3] = f2b(fa0.w);
        A.u[4] = f2b(fa1.x); A.u[5] = f2b(fa1.y); A.u[6] = f2b(fa1.z); A.u[7] = f2b(fa1.w);
        bf16x8 b0 = *(const bf16x8*)(bp0 + kk * 32);
        bf16x8 b1 = *(const bf16x8*)(bp1 + kk * 32);
        bf16x8 b2 = *(const bf16x8*)(bp2 + kk * 32);
        bf16x8 b3 = *(const bf16x8*)(bp3 + kk * 32);
        ac0 = __builtin_amdgcn_mfma_f32_16x16x32_bf16(A.v, b0, ac0, 0, 0, 0);
        ac1 = __builtin_amdgcn_mfma_f32_16x16x32_bf16(A.v, b1, ac1, 0, 0, 0);
        ac2 = __builtin_amdgcn_mfma_f32_16x16x32_bf16(A.v, b2, ac2, 0, 0, 0);
        ac3 = __builtin_amdgcn_mfma_f32_16x16x32_bf16(A.v, b3, ac3, 0, 0, 0);
    }
    int nb = wave * 64;
#pragma unroll
    for (int r = 0; r < 4; r++) {
        int m = m0 + quad * 4 + r;
        if (m < N) {
            unsigned short* op = xp + m * 256 + nb + l16;
            op[0]  = f2b(ac0[r]); op[16] = f2b(ac1[r]);
            op[32] = f2b(ac2[r]); op[48] = f2b(ac3[r]);
        }
    }
}

// ---------------- k1b: a_src/a_dst = x @ u_{src,dst} (fp32, uniform u -> s_loads) --
__global__ __launch_bounds__(256) void k1b_ad(const float* __restrict__ x,
                                              const float* __restrict__ u_src,
                                              const float* __restrict__ u_dst,
                                              float* __restrict__ a_src,
                                              float* __restrict__ a_dst, int N) {
    int n = blockIdx.x * 256 + threadIdx.x;
    if (n >= N) return;
    const float4* xr = (const float4*)(x + n * 256);
    float as[8] = {0,0,0,0,0,0,0,0}, ad[8] = {0,0,0,0,0,0,0,0};
    for (int kk = 0; kk < 64; kk++) {
        float4 u = xr[kk];
        float f[4] = {u.x, u.y, u.z, u.w};
#pragma unroll
        for (int j = 0; j < 4; j++) {
            int k = kk * 4 + j;
#pragma unroll
            for (int h = 0; h < 8; h++) {
                as[h] += f[j] * u_src[k * 8 + h];
                ad[h] += f[j] * u_dst[k * 8 + h];
            }
        }
    }
    float4* po = (float4*)(a_src + n * 8);
    po[0] = make_float4(as[0], as[1], as[2], as[3]);
    po[1] = make_float4(as[4], as[5], as[6], as[7]);
    float4* pd = (float4*)(a_dst + n * 8);
    pd[0] = make_float4(ad[0], ad[1], ad[2], ad[3]);
    pd[1] = make_float4(ad[4], ad[5], ad[6], ad[7]);
}

// ---------------- k2: per-edge logits + exp; ONLY deg atomic (no float atomics) ----
__global__ __launch_bounds__(256) void k2_edge(const int* __restrict__ ei,
                                               const float* __restrict__ eattr,
                                               const float* __restrict__ vW,
                                               const float* __restrict__ a_src,
                                               const float* __restrict__ a_dst,
                                               unsigned short* __restrict__ ea,
                                               int* __restrict__ deg, int E) {
    int e = blockIdx.x * 256 + threadIdx.x;
    if (e >= E) return;
    int s = ei[e], d = ei[E + e];
    float acc[8] = {0,0,0,0,0,0,0,0};
    const float4* ar = (const float4*)(eattr + (size_t)e * 64);
    for (int kk = 0; kk < 16; kk++) {
        float4 u = ar[kk];
        float f[4] = {u.x, u.y, u.z, u.w};
#pragma unroll
        for (int j = 0; j < 4; j++) {
            int k = kk * 4 + j;
#pragma unroll
            for (int h = 0; h < 8; h++) acc[h] += f[j] * vW[k * 8 + h];
        }
    }
    const float4* asp = (const float4*)(a_src + s * 8);
    const float4* adp = (const float4*)(a_dst + d * 8);
    float4 as0 = asp[0], as1 = asp[1], ad0 = adp[0], ad1 = adp[1];
    float asv[8] = {as0.x, as0.y, as0.z, as0.w, as1.x, as1.y, as1.z, as1.w};
    float adv[8] = {ad0.x, ad0.y, ad0.z, ad0.w, ad1.x, ad1.y, ad1.z, ad1.w};
    unsigned short pk[8];
#pragma unroll
    for (int h = 0; h < 8; h++) {
        float al = asv[h] + adv[h] + acc[h];
        al = (al > 0.f) ? al : NEG_SLOPE * al;
        pk[h] = f2b(__expf(al));
    }
    uint4 st;
    st.x = (unsigned)pk[0] | ((unsigned)pk[1] << 16);
    st.y = (unsigned)pk[2] | ((unsigned)pk[3] << 16);
    st.z = (unsigned)pk[4] | ((unsigned)pk[5] << 16);
    st.w = (unsigned)pk[6] | ((unsigned)pk[7] << 16);
    ((uint4*)ea)[e] = st;
    atomicAdd(deg + d, 1);
}

// ---------------- k3: 3-phase exclusive scan of degrees -> CSR rowptr --------------
__global__ __launch_bounds__(1024) void k3a_scan(const int* __restrict__ deg,
                                                 int* __restrict__ rowptr,
                                                 int* __restrict__ bsum, int N) {
    __shared__ int s[1024];
    int t = threadIdx.x, i = blockIdx.x * 1024 + t;
    int v = (i < N) ? deg[i] : 0;
    s[t] = v; __syncthreads();
    for (int off = 1; off < 1024; off <<= 1) {
        int add = (t >= off) ? s[t - off] : 0;
        __syncthreads();
        s[t] += add;
        __syncthreads();
    }
    if (i < N) rowptr[i] = s[t] - v;
    if (t == 1023) bsum[blockIdx.x] = s[1023];
}
__global__ void k3b_scan(const int* __restrict__ bsum, int* __restrict__ boff, int nb) {
    if (threadIdx.x == 0) {
        int run = 0;
        for (int i = 0; i < nb; i++) { boff[i] = run; run += bsum[i]; }
    }
}
__global__ __launch_bounds__(1024) void k3c_add(int* __restrict__ rowptr,
                                                int* __restrict__ cursor,
                                                const int* __restrict__ boff, int N, int E) {
    int i = blockIdx.x * 1024 + threadIdx.x;
    if (i < N) {
        int r = rowptr[i] + boff[blockIdx.x];
        rowptr[i] = r; cursor[i] = r;
    }
    if (i == 0) rowptr[N] = E;
}
__global__ __launch_bounds__(256) void k3d_scatter(const int* __restrict__ ei,
                                                   int* __restrict__ cursor,
                                                   int* __restrict__ perm, int E) {
    int e = blockIdx.x * 256 + threadIdx.x;
    if (e >= E) return;
    int d = ei[E + e];
    int p = atomicAdd(cursor + d, 1);
    perm[p] = e;
}

// ---------------- k4: den reduce + gather + normalize + bias + residual + LN -------
// one wave per node; lane handles 4 channels (head = lane>>3).
__global__ __launch_bounds__(64) void k4_agg(const float* __restrict__ xin,
                                             const unsigned short* __restrict__ xp,
                                             const unsigned short* __restrict__ ea,
                                             const int* __restrict__ rowptr,
                                             const int* __restrict__ perm,
                                             const int* __restrict__ ei,
                                             const float* __restrict__ bias,
                                             const float* __restrict__ gamma,
                                             const float* __restrict__ beta,
                                             float* __restrict__ out, int N) {
    __shared__ int ssrc[64];
    __shared__ float sattn[64 * 9];  // pad 8->9 to break bank conflicts
    int n = blockIdx.x, l = threadIdx.x;
    int start = rowptr[n], end = rowptr[n + 1];

    // ---- pass A: den[h] = sum over incident edges of ea[e][h] (replaces atomics) --
    float dl[8] = {0,0,0,0,0,0,0,0};
    for (int base = start; base < end; base += 64) {
        if (base + l < end) {
            int e = perm[base + l];
            uint4 u = ((const uint4*)ea)[e];
            dl[0] += b2f(u.x & 0xffffu); dl[1] += b2f(u.x >> 16);
            dl[2] += b2f(u.y & 0xffffu); dl[3] += b2f(u.y >> 16);
            dl[4] += b2f(u.z & 0xffffu); dl[5] += b2f(u.z >> 16);
            dl[6] += b2f(u.w & 0xffffu); dl[7] += b2f(u.w >> 16);
        }
    }
#pragma unroll
    for (int off = 32; off > 0; off >>= 1) {
#pragma unroll
        for (int j = 0; j < 8; j++) dl[j] += __shfl_xor(dl[j], off, 64);
    }
    float sinv[8];
#pragma unroll
    for (int j = 0; j < 8; j++) sinv[j] = 1.0f / (dl[j] + 1e-16f);

    // ---- pass B: weighted gather ------------------------------------------------
    float a0 = 0.f, a1 = 0.f, a2 = 0.f, a3 = 0.f;
    int hh = l >> 3;  // head for channels l*4..l*4+3
    for (int base = start; base < end; base += 64) {
        int cnt = end - base; if (cnt > 64) cnt = 64;
        if (l < cnt) {
            int e = perm[base + l];
            ssrc[l] = ei[e];
            uint4 u = ((const uint4*)ea)[e];
            float* sp = sattn + l * 9;
            sp[0] = b2f(u.x & 0xffffu) * sinv[0]; sp[1] = b2f(u.x >> 16) * sinv[1];
            sp[2] = b2f(u.y & 0xffffu) * sinv[2]; sp[3] = b2f(u.y >> 16) * sinv[3];
            sp[4] = b2f(u.z & 0xffffu) * sinv[4]; sp[5] = b2f(u.z >> 16) * sinv[5];
            sp[6] = b2f(u.w & 0xffffu) * sinv[6]; sp[7] = b2f(u.w >> 16) * sinv[7];
        }
        __syncthreads();
        for (int i = 0; i < cnt; i++) {
            int s = ssrc[i];
            uint2 u = *(const uint2*)(xp + s * 256 + l * 4);
            float w = sattn[i * 9 + hh];
            a0 += b2f(u.x & 0xffffu) * w; a1 += b2f(u.x >> 16) * w;
            a2 += b2f(u.y & 0xffffu) * w; a3 += b2f(u.y >> 16) * w;
        }
        __syncthreads();
    }
    float4 xv = *(const float4*)(xin + n * 256 + l * 4);
    float4 bv = *(const float4*)(bias + l * 4);
    float y0 = xv.x + a0 + bv.x;
    float y1 = xv.y + a1 + bv.y;
    float y2 = xv.z + a2 + bv.z;
    float y3 = xv.w + a3 + bv.w;
    float s1 = y0 + y1 + y2 + y3;
    float s2 = y0 * y0 + y1 * y1 + y2 * y2 + y3 * y3;
#pragma unroll
    for (int o = 32; o > 0; o >>= 1) {
        s1 += __shfl_down(s1, o, 64);
        s2 += __shfl_down(s2, o, 64);
    }
    s1 = __shfl(s1, 0, 64); s2 = __shfl(s2, 0, 64);
    float mu = s1 * (1.f / 256.f);
    float var = s2 * (1.f / 256.f) - mu * mu;
    float rs = rsqrtf(var + LN_EPS);
    float4 gv  = *(const float4*)(gamma + l * 4);
    float4 btv = *(const float4*)(beta + l * 4);
    float4 ov;
    ov.x = (y0 - mu) * rs * gv.x + btv.x;
    ov.y = (y1 - mu) * rs * gv.y + btv.y;
    ov.z = (y2 - mu) * rs * gv.z + btv.z;
    ov.w = (y3 - mu) * rs * gv.w + btv.w;
    *(float4*)(out + n * 256 + l * 4) = ov;
}

extern "C" void kernel_launch(void* const* d_in, const int* in_sizes, int n_in,
                              void* d_out, int out_size, void* d_ws, size_t ws_size,
                              hipStream_t stream) {
    const float* x     = (const float*)d_in[0];
    const int*   ei    = (const int*)d_in[1];
    const float* eattr = (const float*)d_in[2];
    const float* W     = (const float*)d_in[3];
    const float* We    = (const float*)d_in[4];
    const float* atts  = (const float*)d_in[5];
    const float* attd  = (const float*)d_in[6];
    const float* atte  = (const float*)d_in[7];
    const float* bias  = (const float*)d_in[8];
    const float* gamma = (const float*)d_in[9];
    const float* beta  = (const float*)d_in[10];
    float* out = (float*)d_out;
    int N = in_sizes[0] / 256;
    int E = in_sizes[1] / 2;

    char* p = (char*)d_ws;
    auto carve = [&](size_t bytes) -> void* {
        void* r = (void*)p; p += (bytes + 255) & ~(size_t)255; return r;
    };
    unsigned short* xp = (unsigned short*)carve((size_t)N * 256 * 2);  // bf16
    unsigned short* ea = (unsigned short*)carve((size_t)E * 8 * 2);    // bf16
    float* a_src       = (float*)carve((size_t)N * 8 * 4);
    float* a_dst       = (float*)carve((size_t)N * 8 * 4);
    int*   deg         = (int*)carve((size_t)N * 4);         // zeroed below
    int*   rowptr      = (int*)carve((size_t)(N + 1) * 4);
    int*   cursor      = (int*)carve((size_t)N * 4);
    int*   perm        = (int*)carve((size_t)E * 4);
    int*   bsum        = (int*)carve(1024);
    int*   boff        = (int*)carve(1024);
    float* u_src       = (float*)carve(2048 * 4);
    float* u_dst       = (float*)carve(2048 * 4);
    float* vW          = (float*)carve(512 * 4);
    unsigned short* Wt = (unsigned short*)carve(65536 * 2);

    hipMemsetAsync(deg, 0, (size_t)N * 4, stream);

    hipLaunchKernelGGL(k0a_prep, dim3(1), dim3(256), 0, stream,
                       W, We, atts, attd, atte, u_src, u_dst, vW);
    hipLaunchKernelGGL(k0b_transpose, dim3(256), dim3(256), 0, stream, W, Wt);
    hipLaunchKernelGGL(k1_xp, dim3((N + 15) / 16), dim3(256), 0, stream, x, Wt, xp, N);
    hipLaunchKernelGGL(k1b_ad, dim3((N + 255) / 256), dim3(256), 0, stream,
                       x, u_src, u_dst, a_src, a_dst, N);
    hipLaunchKernelGGL(k2_edge, dim3((E + 255) / 256), dim3(256), 0, stream,
                       ei, eattr, vW, a_src, a_dst, ea, deg, E);
    int nb = (N + 1023) / 1024;
    hipLaunchKernelGGL(k3a_scan, dim3(nb), dim3(1024), 0, stream, deg, rowptr, bsum, N);
    hipLaunchKernelGGL(k3b_scan, dim3(1), dim3(64), 0, stream, bsum, boff, nb);
    hipLaunchKernelGGL(k3c_add, dim3(nb), dim3(1024), 0, stream, rowptr, cursor, boff, N, E);
    hipLaunchKernelGGL(k3d_scatter, dim3((E + 255) / 256), dim3(256), 0, stream,
                       ei, cursor, perm, E);
    hipLaunchKernelGGL(k4_agg, dim3(N), dim3(64), 0, stream,
                       x, xp, ea, rowptr, perm, ei, bias, gamma, beta, out, N);
}